// Round 1
// baseline (1240.047 us; speedup 1.0000x reference)
//
#include <hip/hip_runtime.h>
#include <math.h>

#define BATCH 2
#define SEQ   2048
#define HID   1024
#define NHEAD 16
#define HDIM  64
#define MTOT  (BATCH * SEQ)   // 4096
#define QKVN  (3 * HID)       // 3072

// ---------------------------------------------------------------------------
// Kernel 1/3: fp32 GEMM with bias.  C[M,N] = A[M,K] @ W[K,N] + bias[N].
// 128x128 tile, BK=8, 256 threads, each thread computes 2x2 blocks of 4x4.
// M,N,K all multiples of 128 here, so no bounds checks.
// ---------------------------------------------------------------------------
__global__ __launch_bounds__(256) void gemm_bias_kernel(
    const float* __restrict__ A, const float* __restrict__ W,
    const float* __restrict__ bias, float* __restrict__ C,
    int M, int N, int K)
{
    __shared__ float As[8][128];   // As[k][m]
    __shared__ float Bs[8][128];   // Bs[k][n]

    const int tid = threadIdx.x;
    const int tx  = tid & 15;      // micro-tile col group
    const int ty  = tid >> 4;      // micro-tile row group
    const int m0  = blockIdx.y * 128;
    const int n0  = blockIdx.x * 128;

    // A-tile load mapping: 128 rows x 8 k, one float4 per thread
    const int a_row = tid >> 1;            // 0..127
    const int a_k   = (tid & 1) * 4;       // 0 or 4
    // B-tile load mapping: 8 rows x 128 n, one float4 per thread
    const int b_row = tid >> 5;            // 0..7
    const int b_col = (tid & 31) * 4;      // 0..124

    float acc[2][2][4][4] = {};

    for (int k0 = 0; k0 < K; k0 += 8) {
        float4 av = *(const float4*)(A + (size_t)(m0 + a_row) * K + k0 + a_k);
        float4 bv = *(const float4*)(W + (size_t)(k0 + b_row) * N + n0 + b_col);
        As[a_k + 0][a_row] = av.x;
        As[a_k + 1][a_row] = av.y;
        As[a_k + 2][a_row] = av.z;
        As[a_k + 3][a_row] = av.w;
        *(float4*)&Bs[b_row][b_col] = bv;
        __syncthreads();

        #pragma unroll
        for (int kk = 0; kk < 8; ++kk) {
            float4 a0 = *(const float4*)&As[kk][ty * 4];
            float4 a1 = *(const float4*)&As[kk][64 + ty * 4];
            float4 b0 = *(const float4*)&Bs[kk][tx * 4];
            float4 b1 = *(const float4*)&Bs[kk][64 + tx * 4];
            float am[2][4] = {{a0.x, a0.y, a0.z, a0.w}, {a1.x, a1.y, a1.z, a1.w}};
            float bn[2][4] = {{b0.x, b0.y, b0.z, b0.w}, {b1.x, b1.y, b1.z, b1.w}};
            #pragma unroll
            for (int i = 0; i < 2; ++i)
                #pragma unroll
                for (int j = 0; j < 2; ++j)
                    #pragma unroll
                    for (int r = 0; r < 4; ++r)
                        #pragma unroll
                        for (int c = 0; c < 4; ++c)
                            acc[i][j][r][c] += am[i][r] * bn[j][c];
        }
        __syncthreads();
    }

    #pragma unroll
    for (int i = 0; i < 2; ++i) {
        #pragma unroll
        for (int r = 0; r < 4; ++r) {
            const int m = m0 + i * 64 + ty * 4 + r;
            #pragma unroll
            for (int j = 0; j < 2; ++j) {
                const int n = n0 + j * 64 + tx * 4;
                float4 v;
                v.x = acc[i][j][r][0] + bias[n + 0];
                v.y = acc[i][j][r][1] + bias[n + 1];
                v.z = acc[i][j][r][2] + bias[n + 2];
                v.w = acc[i][j][r][3] + bias[n + 3];
                *(float4*)(C + (size_t)m * N + n) = v;
            }
        }
    }
}

// ---------------------------------------------------------------------------
// Kernel 2: fused causal attention (flash-style single pass, fp32).
// Grid: (SEQ/16, NHEAD, BATCH), 256 threads.
// Each block: 16 query rows of one (batch, head).
// Score phase mapping:  ty = row (0..15), tx = key-in-tile (0..15)
// PV phase mapping:     pr = row (0..15) [== ty], pc4 = 4-col group
// Online softmax state (m, l, alpha) lives in registers; 16-lane shuffles.
// Mask semantics match reference exactly: masked score = -10000.0f.
// ---------------------------------------------------------------------------
#define QT 16
#define KT 16
#define LP 68   // padded LDS leading dim (16B-aligned rows, no bank conflicts)

__global__ __launch_bounds__(256) void attn_kernel(
    const float* __restrict__ qkv, float* __restrict__ ctx)
{
    const int qt0 = blockIdx.x * QT;
    const int h   = blockIdx.y;
    const int b   = blockIdx.z;
    const int tid = threadIdx.x;
    const int tx  = tid & 15;
    const int ty  = tid >> 4;
    const int pc4 = (tid & 15) * 4;   // PV column group (same lanes as tx)

    __shared__ float Qs[QT][LP];
    __shared__ float Ks[KT][LP];
    __shared__ float Vs[KT][LP];
    __shared__ float sc[QT][KT];      // exp(s - m) tile

    // stage Q tile (one float4 per thread: 16 rows x 64 cols)
    const int s_row = tid >> 4;
    const int s_c4  = (tid & 15) * 4;
    {
        const float* qbase = qkv + ((size_t)(b * SEQ + qt0 + s_row)) * QKVN
                                 + h * HDIM + s_c4;
        *(float4*)&Qs[s_row][s_c4] = *(const float4*)qbase;
    }
    __syncthreads();

    // this thread's query row into registers (64 floats)
    float4 q[16];
    #pragma unroll
    for (int i = 0; i < 16; ++i) q[i] = *(const float4*)&Qs[ty][i * 4];

    const int qg = qt0 + ty;          // global query index (score phase)
    float m_r = -INFINITY;
    float l_r = 0.0f;
    float acc[4] = {0.f, 0.f, 0.f, 0.f};

    const int ntiles = blockIdx.x + 1;   // causal: keys only up to qt0+15

    for (int t = 0; t < ntiles; ++t) {
        const int kt0 = t * KT;
        // stage K and V tiles
        {
            const float* kbase = qkv + ((size_t)(b * SEQ + kt0 + s_row)) * QKVN
                                     + HID + h * HDIM + s_c4;
            *(float4*)&Ks[s_row][s_c4] = *(const float4*)kbase;
            *(float4*)&Vs[s_row][s_c4] = *(const float4*)(kbase + HID);
        }
        __syncthreads();

        // --- scores: s = (q . k) / sqrt(64), causal mask -> -10000
        float s = 0.0f;
        #pragma unroll
        for (int i = 0; i < 16; ++i) {
            float4 kv = *(const float4*)&Ks[tx][i * 4];
            s += q[i].x * kv.x + q[i].y * kv.y + q[i].z * kv.z + q[i].w * kv.w;
        }
        s *= 0.125f;
        const int kg = kt0 + tx;
        if (kg > qg) s = -10000.0f;

        // --- online softmax over the 16-lane row group
        float tmax = s;
        tmax = fmaxf(tmax, __shfl_xor(tmax, 1));
        tmax = fmaxf(tmax, __shfl_xor(tmax, 2));
        tmax = fmaxf(tmax, __shfl_xor(tmax, 4));
        tmax = fmaxf(tmax, __shfl_xor(tmax, 8));
        const float new_m = fmaxf(m_r, tmax);
        const float e     = __expf(s - new_m);
        float tsum = e;
        tsum += __shfl_xor(tsum, 1);
        tsum += __shfl_xor(tsum, 2);
        tsum += __shfl_xor(tsum, 4);
        tsum += __shfl_xor(tsum, 8);
        const float alpha = __expf(m_r - new_m);   // 0 on first tile (m_r=-inf)
        l_r = l_r * alpha + tsum;
        m_r = new_m;
        sc[ty][tx] = e;
        __syncthreads();

        // --- PV: row = ty, cols pc4..pc4+3
        acc[0] *= alpha; acc[1] *= alpha; acc[2] *= alpha; acc[3] *= alpha;
        #pragma unroll
        for (int kk = 0; kk < KT; ++kk) {
            const float p = sc[ty][kk];               // broadcast read
            float4 v = *(const float4*)&Vs[kk][pc4];
            acc[0] += p * v.x;
            acc[1] += p * v.y;
            acc[2] += p * v.z;
            acc[3] += p * v.w;
        }
        __syncthreads();   // before next tile overwrites Ks/Vs/sc
    }

    const float inv = 1.0f / l_r;
    float4 o;
    o.x = acc[0] * inv; o.y = acc[1] * inv; o.z = acc[2] * inv; o.w = acc[3] * inv;
    *(float4*)(ctx + ((size_t)(b * SEQ + qt0 + ty)) * HID + h * HDIM + pc4) = o;
}

// ---------------------------------------------------------------------------
// Launch: QKV GEMM -> fused attention -> dense GEMM (writes d_out).
// Workspace layout: qkv [4096 x 3072] fp32, ctx [4096 x 1024] fp32 (67.1 MB).
// ---------------------------------------------------------------------------
extern "C" void kernel_launch(void* const* d_in, const int* in_sizes, int n_in,
                              void* d_out, int out_size, void* d_ws, size_t ws_size,
                              hipStream_t stream) {
    const float* hs   = (const float*)d_in[0];
    // d_in[1] = ltor_mask: deterministic causal tril, implemented analytically
    const float* Wqkv = (const float*)d_in[2];
    const float* bqkv = (const float*)d_in[3];
    const float* Wd   = (const float*)d_in[4];
    const float* bd   = (const float*)d_in[5];
    float* out = (float*)d_out;

    float* qkv = (float*)d_ws;                          // 4096*3072 fp32
    float* ctx = qkv + (size_t)MTOT * QKVN;             // 4096*1024 fp32

    dim3 g1(QKVN / 128, MTOT / 128);                    // (24, 32)
    gemm_bias_kernel<<<g1, 256, 0, stream>>>(hs, Wqkv, bqkv, qkv, MTOT, QKVN, HID);

    dim3 g2(SEQ / QT, NHEAD, BATCH);                    // (128, 16, 2)
    attn_kernel<<<g2, 256, 0, stream>>>(qkv, ctx);

    dim3 g3(HID / 128, MTOT / 128);                     // (8, 32)
    gemm_bias_kernel<<<g3, 256, 0, stream>>>(ctx, Wd, bd, out, MTOT, HID, HID);
}

// Round 2
// 286.801 us; speedup vs baseline: 4.3237x; 4.3237x over previous
//
#include <hip/hip_runtime.h>
#include <math.h>

#define BATCH 2
#define SEQ   2048
#define HID   1024
#define NHEAD 16
#define HDIM  64
#define MTOT  (BATCH * SEQ)   // 4096
#define QKVN  (3 * HID)       // 3072
#define HBUF  ((size_t)BATCH * NHEAD * SEQ * HDIM)   // 4194304 elems per q/k/v buf

typedef _Float16 f16x8 __attribute__((ext_vector_type(8)));
typedef _Float16 f16x4 __attribute__((ext_vector_type(4)));
typedef float    f32x4 __attribute__((ext_vector_type(4)));

#define MFMA16(a, b, c) __builtin_amdgcn_mfma_f32_16x16x32_f16((a), (b), (c), 0, 0, 0)

// async global->LDS, 16B per lane, LDS dest = base + lane*16 (wave-uniform base)
#define GLDS16(gp, lp) __builtin_amdgcn_global_load_lds( \
    (const __attribute__((address_space(1))) void*)(gp), \
    (__attribute__((address_space(3))) void*)(lp), 16, 0, 0)

// ---------------------------------------------------------------------------
// fp32 -> fp16 elementwise convert (8 elems/thread, 16B stores)
// ---------------------------------------------------------------------------
__global__ __launch_bounds__(256) void convert_f32_f16(
    const float* __restrict__ in, _Float16* __restrict__ out)
{
    const size_t i = ((size_t)blockIdx.x * 256 + threadIdx.x) * 8;
    float4 a = *(const float4*)(in + i);
    float4 b = *(const float4*)(in + i + 4);
    f16x8 o;
    o[0] = (_Float16)a.x; o[1] = (_Float16)a.y; o[2] = (_Float16)a.z; o[3] = (_Float16)a.w;
    o[4] = (_Float16)b.x; o[5] = (_Float16)b.y; o[6] = (_Float16)b.z; o[7] = (_Float16)b.w;
    *(f16x8*)(out + i) = o;
}

// ---------------------------------------------------------------------------
// fp32 [K][N] -> fp16 [N][K] transpose-convert (32x32 tiles via LDS)
// ---------------------------------------------------------------------------
__global__ __launch_bounds__(256) void transpose_convert(
    const float* __restrict__ in, _Float16* __restrict__ out, int K, int N)
{
    __shared__ _Float16 T[32][36];
    const int k0 = blockIdx.y * 32, n0 = blockIdx.x * 32;
    const int tid = threadIdx.x;
    {
        const int r = tid >> 3, c4 = (tid & 7) * 4;
        float4 v = *(const float4*)(in + (size_t)(k0 + r) * N + n0 + c4);
        T[r][c4 + 0] = (_Float16)v.x;
        T[r][c4 + 1] = (_Float16)v.y;
        T[r][c4 + 2] = (_Float16)v.z;
        T[r][c4 + 3] = (_Float16)v.w;
    }
    __syncthreads();
    {
        const int nn = tid >> 3, k4 = (tid & 7) * 4;
        f16x4 o;
        o[0] = T[k4 + 0][nn]; o[1] = T[k4 + 1][nn];
        o[2] = T[k4 + 2][nn]; o[3] = T[k4 + 3][nn];
        *(f16x4*)(out + (size_t)(n0 + nn) * K + k0 + k4) = o;
    }
}

// ---------------------------------------------------------------------------
// MFMA fp16 GEMM: C[M,N] = A[M,K] @ Bt[N,K]^T + bias.
// 128x128 tile, BK=32, 4 waves in 2x2, each wave 4x4 of 16x16x32 MFMA.
// EPI=0: scatter to q/k/v bufs [b][h][s][d] as fp16 (Cout = q_buf base).
// EPI=1: plain fp32 [M][N] store.
// ---------------------------------------------------------------------------
template<int EPI>
__global__ __launch_bounds__(256) void mfma_gemm(
    const _Float16* __restrict__ A, const _Float16* __restrict__ Bt,
    const float* __restrict__ bias, void* __restrict__ Cout,
    int M, int N, int K)
{
    __shared__ _Float16 As[128 * 32];
    __shared__ _Float16 Bs[128 * 32];

    const int tid = threadIdx.x;
    const int w = tid >> 6, l = tid & 63;
    const int a = l & 15, q4 = l >> 4;
    const int m0 = blockIdx.y * 128, n0 = blockIdx.x * 128;
    const int wm = (w >> 1) * 64, wn = (w & 1) * 64;

    f32x4 acc[4][4];
#pragma unroll
    for (int i = 0; i < 4; ++i)
#pragma unroll
        for (int j = 0; j < 4; ++j) acc[i][j] = (f32x4){0.f, 0.f, 0.f, 0.f};

    // staging: wave w covers rows w*32 .. w*32+31 of the 128-row tile, 2 issues
    const _Float16* gA = A + (size_t)(m0 + w * 32 + (l >> 2)) * K + (l & 3) * 8;
    const _Float16* gB = Bt + (size_t)(n0 + w * 32 + (l >> 2)) * K + (l & 3) * 8;
    _Float16* sA = As + w * 1024;
    _Float16* sB = Bs + w * 1024;

    for (int k0 = 0; k0 < K; k0 += 32) {
        GLDS16(gA + k0,          sA);
        GLDS16(gA + 16 * K + k0, sA + 512);
        GLDS16(gB + k0,          sB);
        GLDS16(gB + 16 * K + k0, sB + 512);
        __syncthreads();

        f16x8 af[4], bf[4];
#pragma unroll
        for (int i = 0; i < 4; ++i)
            af[i] = *(const f16x8*)&As[(wm + 16 * i + a) * 32 + q4 * 8];
#pragma unroll
        for (int j = 0; j < 4; ++j)
            bf[j] = *(const f16x8*)&Bs[(wn + 16 * j + a) * 32 + q4 * 8];
#pragma unroll
        for (int i = 0; i < 4; ++i)
#pragma unroll
            for (int j = 0; j < 4; ++j)
                acc[i][j] = MFMA16(af[i], bf[j], acc[i][j]);
        __syncthreads();
    }

    if (EPI == 0) {
        _Float16* base = (_Float16*)Cout;
#pragma unroll
        for (int j = 0; j < 4; ++j) {
            const int n = n0 + wn + 16 * j + a;
            const float bv = bias[n];
            const int t = n >> 10, h = (n >> 6) & 15, d = n & 63;
            _Float16* tb = base + (size_t)t * HBUF;
#pragma unroll
            for (int i = 0; i < 4; ++i) {
#pragma unroll
                for (int r = 0; r < 4; ++r) {
                    const int m = m0 + wm + 16 * i + q4 * 4 + r;
                    const int bb = m >> 11, s = m & 2047;
                    tb[((size_t)((bb << 4) + h) * 2048 + s) * 64 + d] =
                        (_Float16)(acc[i][j][r] + bv);
                }
            }
        }
    } else {
        float* C = (float*)Cout;
#pragma unroll
        for (int j = 0; j < 4; ++j) {
            const int n = n0 + wn + 16 * j + a;
            const float bv = bias[n];
#pragma unroll
            for (int i = 0; i < 4; ++i) {
#pragma unroll
                for (int r = 0; r < 4; ++r) {
                    const int m = m0 + wm + 16 * i + q4 * 4 + r;
                    C[(size_t)m * N + n] = acc[i][j][r] + bv;
                }
            }
        }
    }
}

// ---------------------------------------------------------------------------
// MFMA flash attention, causal. Block = 64 queries of one (b,h); 4 waves,
// wave w owns queries [qt0+16w, qt0+16w+16). K-tile = 64 keys.
// Per tile: 8 QK MFMAs -> fp32 online softmax (reg-resident stats) ->
// P via per-wave LDS round-trip -> 8 PV MFMAs. Vt double-buffered, 2 barriers.
// All LDS strides padded to 72 fp16 (144 B) to break power-of-2 bank aliasing.
// ---------------------------------------------------------------------------
#define ATP 72

__global__ __launch_bounds__(256) void attn_mfma(
    const _Float16* __restrict__ qb, const _Float16* __restrict__ kb,
    const _Float16* __restrict__ vb, _Float16* __restrict__ ctx)
{
    __shared__ _Float16 Ks[64 * ATP];
    __shared__ _Float16 VT[2][64 * ATP];
    __shared__ _Float16 Ps[4][16 * ATP];

    const int qt = blockIdx.x, h = blockIdx.y, b = blockIdx.z;
    const int qt0 = qt * 64;
    const int tid = threadIdx.x;
    const int w = tid >> 6, l = tid & 63;
    const int a = l & 15, q4 = l >> 4;
    const size_t bh = ((size_t)b * NHEAD + h) * SEQ;

    // Q fragments: lane holds Q[m=a][k=q4*8+j] for both 32-wide k-steps
    f16x8 qf[2];
    {
        const _Float16* qp = qb + (bh + qt0 + w * 16 + a) * 64 + q4 * 8;
        qf[0] = *(const f16x8*)qp;
        qf[1] = *(const f16x8*)(qp + 32);
    }

    f32x4 O[4];
#pragma unroll
    for (int c = 0; c < 4; ++c) O[c] = (f32x4){0.f, 0.f, 0.f, 0.f};
    float mrow[4] = {-INFINITY, -INFINITY, -INFINITY, -INFINITY};
    float lrow[4] = {0.f, 0.f, 0.f, 0.f};

    for (int t = 0; t <= qt; ++t) {
        const int kt0 = t * 64;
        // --- stage K (contiguous 8KB tile -> padded rows, b128 writes)
        {
            const uint4* src = (const uint4*)(kb + (bh + kt0) * 64);
            uint4 x0 = src[tid * 2], x1 = src[tid * 2 + 1];
            const int kr = tid >> 2, kc = (tid & 3) * 16;
            *(uint4*)&Ks[kr * ATP + kc]     = x0;
            *(uint4*)&Ks[kr * ATP + kc + 8] = x1;
        }
        // --- stage V transposed: wave w writes hd-cols [16w,16w+16), key=l
        {
            const _Float16* vp = vb + (bh + kt0 + l) * 64 + w * 16;
            f16x8 v0 = *(const f16x8*)vp;
            f16x8 v1 = *(const f16x8*)(vp + 8);
            _Float16* dst = &VT[t & 1][0];
#pragma unroll
            for (int jj = 0; jj < 8; ++jj) dst[(w * 16 + jj) * ATP + l] = v0[jj];
#pragma unroll
            for (int jj = 0; jj < 8; ++jj) dst[(w * 16 + 8 + jj) * ATP + l] = v1[jj];
        }
        __syncthreads();   // B1: tiles visible

        // --- QK^T: 4 key subtiles x (K=64 as 2 MFMA k-steps)
        f32x4 sf[4];
#pragma unroll
        for (int n0 = 0; n0 < 4; ++n0) {
            f16x8 kf0 = *(const f16x8*)&Ks[(n0 * 16 + a) * ATP + q4 * 8];
            f16x8 kf1 = *(const f16x8*)&Ks[(n0 * 16 + a) * ATP + 32 + q4 * 8];
            f32x4 c = (f32x4){0.f, 0.f, 0.f, 0.f};
            c = MFMA16(qf[0], kf0, c);
            c = MFMA16(qf[1], kf1, c);
            sf[n0] = c;
        }
        // scale + causal mask (only the diagonal tile needs masking)
        if (t == qt) {
#pragma unroll
            for (int n0 = 0; n0 < 4; ++n0)
#pragma unroll
                for (int r = 0; r < 4; ++r) {
                    const int kg = n0 * 16 + a;
                    const int qg = w * 16 + q4 * 4 + r;
                    sf[n0][r] = (kg > qg) ? -10000.0f : sf[n0][r] * 0.125f;
                }
        } else {
#pragma unroll
            for (int n0 = 0; n0 < 4; ++n0) sf[n0] *= 0.125f;
        }

        // --- online softmax (rows live in 16-lane groups)
        float nm[4], al[4];
#pragma unroll
        for (int r = 0; r < 4; ++r) {
            float mx = fmaxf(fmaxf(sf[0][r], sf[1][r]), fmaxf(sf[2][r], sf[3][r]));
            mx = fmaxf(mx, __shfl_xor(mx, 1));
            mx = fmaxf(mx, __shfl_xor(mx, 2));
            mx = fmaxf(mx, __shfl_xor(mx, 4));
            mx = fmaxf(mx, __shfl_xor(mx, 8));
            nm[r] = fmaxf(mrow[r], mx);
            al[r] = __expf(mrow[r] - nm[r]);
            mrow[r] = nm[r];
        }
        float rs[4] = {0.f, 0.f, 0.f, 0.f};
#pragma unroll
        for (int n0 = 0; n0 < 4; ++n0)
#pragma unroll
            for (int r = 0; r < 4; ++r) {
                const float p = __expf(sf[n0][r] - nm[r]);
                sf[n0][r] = p;
                rs[r] += p;
            }
#pragma unroll
        for (int r = 0; r < 4; ++r) {
            rs[r] += __shfl_xor(rs[r], 1);
            rs[r] += __shfl_xor(rs[r], 2);
            rs[r] += __shfl_xor(rs[r], 4);
            rs[r] += __shfl_xor(rs[r], 8);
            lrow[r] = lrow[r] * al[r] + rs[r];
        }
        // rescale O, stash P (fp16) for the LDS round-trip
#pragma unroll
        for (int c = 0; c < 4; ++c)
#pragma unroll
            for (int r = 0; r < 4; ++r) O[c][r] *= al[r];
#pragma unroll
        for (int n0 = 0; n0 < 4; ++n0)
#pragma unroll
            for (int r = 0; r < 4; ++r)
                Ps[w][(q4 * 4 + r) * ATP + n0 * 16 + a] = (_Float16)sf[n0][r];
        __syncthreads();   // B2: P visible (and Ks reads drained)

        // --- PV: P[16x64] @ V[64x64]
        f16x8 pf0 = *(const f16x8*)&Ps[w][a * ATP + q4 * 8];
        f16x8 pf1 = *(const f16x8*)&Ps[w][a * ATP + 32 + q4 * 8];
        const _Float16* vt = &VT[t & 1][0];
#pragma unroll
        for (int c = 0; c < 4; ++c) {
            f16x8 vf0 = *(const f16x8*)&vt[(c * 16 + a) * ATP + q4 * 8];
            f16x8 vf1 = *(const f16x8*)&vt[(c * 16 + a) * ATP + 32 + q4 * 8];
            O[c] = MFMA16(pf0, vf0, O[c]);
            O[c] = MFMA16(pf1, vf1, O[c]);
        }
    }

    // epilogue: O/l -> ctx fp16 [b*S+s][h*64+d]
#pragma unroll
    for (int r = 0; r < 4; ++r) {
        const float inv = 1.0f / lrow[r];
        const size_t row = (size_t)b * SEQ + qt0 + w * 16 + q4 * 4 + r;
#pragma unroll
        for (int c = 0; c < 4; ++c)
            ctx[row * HID + h * 64 + c * 16 + a] = (_Float16)(O[c][r] * inv);
    }
}

// ---------------------------------------------------------------------------
// Workspace: A_h | WqkvT | WdT | q_buf | k_buf | v_buf | ctx   (all fp16)
// ---------------------------------------------------------------------------
extern "C" void kernel_launch(void* const* d_in, const int* in_sizes, int n_in,
                              void* d_out, int out_size, void* d_ws, size_t ws_size,
                              hipStream_t stream) {
    const float* hs   = (const float*)d_in[0];
    const float* Wqkv = (const float*)d_in[2];
    const float* bqkv = (const float*)d_in[3];
    const float* Wd   = (const float*)d_in[4];
    const float* bd   = (const float*)d_in[5];

    _Float16* A_h   = (_Float16*)d_ws;                       // 4096x1024
    _Float16* WqkvT = A_h + (size_t)MTOT * HID;              // 3072x1024
    _Float16* WdT   = WqkvT + (size_t)QKVN * HID;            // 1024x1024
    _Float16* qbuf  = WdT + (size_t)HID * HID;               // 3 x HBUF
    _Float16* ctxb  = qbuf + 3 * HBUF;                       // 4096x1024

    convert_f32_f16<<<(MTOT * HID) / (256 * 8), 256, 0, stream>>>(hs, A_h);
    transpose_convert<<<dim3(QKVN / 32, HID / 32), 256, 0, stream>>>(Wqkv, WqkvT, HID, QKVN);
    transpose_convert<<<dim3(HID / 32, HID / 32), 256, 0, stream>>>(Wd, WdT, HID, HID);

    mfma_gemm<0><<<dim3(QKVN / 128, MTOT / 128), 256, 0, stream>>>(
        A_h, WqkvT, bqkv, (void*)qbuf, MTOT, QKVN, HID);

    attn_mfma<<<dim3(SEQ / 64, NHEAD, BATCH), 256, 0, stream>>>(
        qbuf, qbuf + HBUF, qbuf + 2 * HBUF, ctxb);

    mfma_gemm<1><<<dim3(HID / 128, MTOT / 128), 256, 0, stream>>>(
        ctxb, WdT, bd, d_out, MTOT, HID, HID);
}

// Round 3
// 243.048 us; speedup vs baseline: 5.1021x; 1.1800x over previous
//
#include <hip/hip_runtime.h>
#include <math.h>

#define BATCH 2
#define SEQ   2048
#define HID   1024
#define NHEAD 16
#define HDIM  64
#define MTOT  (BATCH * SEQ)   // 4096
#define QKVN  (3 * HID)       // 3072
#define HBUF  ((size_t)BATCH * NHEAD * SEQ * HDIM)   // elems per q/k/vT buf

typedef _Float16 f16x8 __attribute__((ext_vector_type(8)));
typedef _Float16 f16x4 __attribute__((ext_vector_type(4)));
typedef float    f32x4 __attribute__((ext_vector_type(4)));

#define MFMA16(a, b, c) __builtin_amdgcn_mfma_f32_16x16x32_f16((a), (b), (c), 0, 0, 0)

#define GLDS16(gp, lp) __builtin_amdgcn_global_load_lds( \
    (const __attribute__((address_space(1))) void*)(gp), \
    (__attribute__((address_space(3))) void*)(lp), 16, 0, 0)

#if __has_builtin(__builtin_amdgcn_exp2f)
#define EXP2F(x) __builtin_amdgcn_exp2f(x)
#else
#define EXP2F(x) exp2f(x)
#endif

#define SCALE2 0.18033688011f     // 0.125 * log2(e)
#define MASK2  -14426.950408f     // -10000 * log2(e)

// ---------------------------------------------------------------------------
// fp32 -> fp16 convert with GEMM-A swizzle: within each 32-elem k-group,
// 16B chunk c of row m is stored at position c ^ (m&3).  (K = 1024.)
// One thread = one 16B chunk (8 elems).
// ---------------------------------------------------------------------------
__global__ __launch_bounds__(256) void convert_f32_f16(
    const float* __restrict__ in, _Float16* __restrict__ out)
{
    const int ci = blockIdx.x * 256 + threadIdx.x;      // global chunk id
    const int m = ci >> 7, cc = ci & 127;               // 128 chunks per row
    const int g = cc >> 2, c = cc & 3;
    const float* src = in + (size_t)m * 1024 + cc * 8;
    f16x8 o;
#pragma unroll
    for (int j = 0; j < 8; ++j) o[j] = (_Float16)src[j];
    *(f16x8*)(out + (size_t)m * 1024 + g * 32 + ((c ^ (m & 3)) << 3)) = o;
}

// ---------------------------------------------------------------------------
// fp32 [K][N] -> fp16 [N][K] transpose-convert, with the same per-32-group
// chunk swizzle keyed on the destination row n (B operand of the GEMM).
// ---------------------------------------------------------------------------
__global__ __launch_bounds__(256) void transpose_convert(
    const float* __restrict__ in, _Float16* __restrict__ out, int K, int N)
{
    __shared__ _Float16 T[32][36];
    const int k0 = blockIdx.y * 32, n0 = blockIdx.x * 32;
    const int tid = threadIdx.x;
    {
        const int r = tid >> 3, c4 = (tid & 7) * 4;
        float4 v = *(const float4*)(in + (size_t)(k0 + r) * N + n0 + c4);
        T[r][c4 + 0] = (_Float16)v.x;
        T[r][c4 + 1] = (_Float16)v.y;
        T[r][c4 + 2] = (_Float16)v.z;
        T[r][c4 + 3] = (_Float16)v.w;
    }
    __syncthreads();
    {
        const int nn = tid >> 3, k4 = (tid & 7) * 4;
        const int n = n0 + nn;
        f16x4 o;
        o[0] = T[k4 + 0][nn]; o[1] = T[k4 + 1][nn];
        o[2] = T[k4 + 2][nn]; o[3] = T[k4 + 3][nn];
        const int pos = ((k4 >> 3) ^ (n & 3)), half = (k4 >> 2) & 1;
        *(f16x4*)(out + (size_t)n * K + k0 + pos * 8 + half * 4) = o;
    }
}

// ---------------------------------------------------------------------------
// MFMA fp16 GEMM, 128x128xBK32, swizzled LDS (conflict-free b128 reads).
// A and Bt are pre-swizzled in global, so global_load_lds is an identity copy.
// EPI=0: scatter to q (plain) / k (row-swizzled) / vT (transposed+swizzled).
// EPI=1: plain fp32 store.
// ---------------------------------------------------------------------------
template<int EPI>
__global__ __launch_bounds__(256) void mfma_gemm(
    const _Float16* __restrict__ A, const _Float16* __restrict__ Bt,
    const float* __restrict__ bias, void* __restrict__ Cout,
    int M, int N, int K)
{
    __shared__ _Float16 As[128 * 32];
    __shared__ _Float16 Bs[128 * 32];

    const int tid = threadIdx.x;
    const int w = tid >> 6, l = tid & 63;
    const int a = l & 15, q4 = l >> 4;
    const int m0 = blockIdx.y * 128, n0 = blockIdx.x * 128;
    const int wm = (w >> 1) * 64, wn = (w & 1) * 64;

    f32x4 acc[4][4];
#pragma unroll
    for (int i = 0; i < 4; ++i)
#pragma unroll
        for (int j = 0; j < 4; ++j) acc[i][j] = (f32x4){0.f, 0.f, 0.f, 0.f};

    const _Float16* gA = A + (size_t)(m0 + w * 32 + (l >> 2)) * K + (l & 3) * 8;
    const _Float16* gB = Bt + (size_t)(n0 + w * 32 + (l >> 2)) * K + (l & 3) * 8;
    _Float16* sA = As + w * 1024;
    _Float16* sB = Bs + w * 1024;

    for (int k0 = 0; k0 < K; k0 += 32) {
        GLDS16(gA + k0,          sA);
        GLDS16(gA + 16 * K + k0, sA + 512);
        GLDS16(gB + k0,          sB);
        GLDS16(gB + 16 * K + k0, sB + 512);
        __syncthreads();

        f16x8 af[4], bf[4];
        const int pa = (q4 ^ (a & 3)) << 3;
#pragma unroll
        for (int i = 0; i < 4; ++i)
            af[i] = *(const f16x8*)&As[(wm + 16 * i + a) * 32 + pa];
#pragma unroll
        for (int j = 0; j < 4; ++j)
            bf[j] = *(const f16x8*)&Bs[(wn + 16 * j + a) * 32 + pa];
#pragma unroll
        for (int i = 0; i < 4; ++i)
#pragma unroll
            for (int j = 0; j < 4; ++j)
                acc[i][j] = MFMA16(af[i], bf[j], acc[i][j]);
        __syncthreads();
    }

    if (EPI == 0) {
        _Float16* base = (_Float16*)Cout;
#pragma unroll
        for (int j = 0; j < 4; ++j) {
            const int n = n0 + wn + 16 * j + a;
            const float bv = bias[n];
            const int t = n >> 10, h = (n >> 6) & 15, d = n & 63;
#pragma unroll
            for (int i = 0; i < 4; ++i) {
#pragma unroll
                for (int r = 0; r < 4; ++r) {
                    const int m = m0 + wm + 16 * i + q4 * 4 + r;
                    const int bb = m >> 11, s = m & 2047;
                    const _Float16 val = (_Float16)(acc[i][j][r] + bv);
                    if (t == 0) {
                        base[((size_t)(bb * 16 + h) * 2048 + s) * 64 + d] = val;
                    } else if (t == 1) {
                        const int dk = ((((d >> 3) ^ (s & 7)) & 7) << 3) | (d & 7);
                        base[HBUF + ((size_t)(bb * 16 + h) * 2048 + s) * 64 + dk] = val;
                    } else {
                        const int sk = (s & ~63) | ((((s >> 3) & 7) ^ (d & 7)) << 3) | (s & 7);
                        base[2 * HBUF + ((size_t)(bb * 16 + h) * 64 + d) * 2048 + sk] = val;
                    }
                }
            }
        }
    } else {
        float* C = (float*)Cout;
#pragma unroll
        for (int j = 0; j < 4; ++j) {
            const int n = n0 + wn + 16 * j + a;
            const float bv = bias[n];
#pragma unroll
            for (int i = 0; i < 4; ++i)
#pragma unroll
                for (int r = 0; r < 4; ++r) {
                    const int m = m0 + wm + 16 * i + q4 * 4 + r;
                    C[(size_t)m * N + n] = acc[i][j][r] + bv;
                }
        }
    }
}

// ---------------------------------------------------------------------------
// Transposed-MFMA flash attention, causal.
// Block = 128 queries of one (b,h); wave w owns queries [128*qt + 32w, +32).
// S^T = MFMA(Kf, Qf)  (rows=key, cols=query=lane) -> per-lane softmax stats
// (2 shuffles/16q for max; l-sum reduced once at the end).
// O^T = MFMA(VTf, Pf); V pre-transposed+swizzled in global by QKV epilogue.
// LDS 24 KB: Ks 8K + VT dbuf 16K; P reuses wave's own slice of inactive VT.
// All tiles use chunk^(row&7) swizzle -> conflict-free ds_read_b128.
// ---------------------------------------------------------------------------
__global__ __launch_bounds__(256) void attn_mfma(
    const _Float16* __restrict__ qb, const _Float16* __restrict__ kb,
    const _Float16* __restrict__ vtb, _Float16* __restrict__ ctx)
{
    __shared__ _Float16 Ks[64 * 64];
    __shared__ _Float16 VT[2][64 * 64];

    const int qt = (gridDim.x - 1) - blockIdx.x;   // heavy blocks first
    const int h = blockIdx.y, b = blockIdx.z;
    const int qt0 = qt * 128;
    const int tid = threadIdx.x;
    const int w = tid >> 6, l = tid & 63;
    const int a = l & 15, q4 = l >> 4;
    const int a7 = a & 7;
    const size_t bh  = ((size_t)b * NHEAD + h) * SEQ;
    const size_t bhd = ((size_t)b * NHEAD + h) * 64;

    // Q fragments (global, unswizzled): lane holds Q[q=qw0+m0*16+a][k-chunks q4, q4+4]
    const int qw0 = qt0 + w * 32;
    f16x8 qf[2][2];
#pragma unroll
    for (int m0 = 0; m0 < 2; ++m0) {
        const _Float16* qp = qb + (bh + qw0 + m0 * 16 + a) * 64;
        qf[m0][0] = *(const f16x8*)(qp + q4 * 8);
        qf[m0][1] = *(const f16x8*)(qp + 32 + q4 * 8);
    }

    f32x4 O[2][4];
#pragma unroll
    for (int m0 = 0; m0 < 2; ++m0)
#pragma unroll
        for (int c = 0; c < 4; ++c) O[m0][c] = (f32x4){0.f, 0.f, 0.f, 0.f};
    float mrun[2] = {-INFINITY, -INFINITY};
    float lrun[2] = {0.f, 0.f};

    // staging bases: wave w stages rows [16w, 16w+16) of Ks and of VT[t&1]
    const _Float16* kg = kb + (bh + w * 16) * 64 + l * 8;          // contiguous
    _Float16* ksl = Ks + w * 16 * 64 + l * 8;
    const int vrow = w * 16 + (l >> 3);
    const _Float16* vg = vtb + (bhd + vrow) * 2048 + (l & 7) * 8;  // per-lane gather

    const int ntiles = 2 * qt + 2;

    for (int t = 0; t < ntiles; ++t) {
        const int kt0 = t * 64;
        _Float16* vbuf = &VT[t & 1][0];
        _Float16* pbuf = &VT[(t + 1) & 1][0] + w * 16 * 64;  // wave-private 2KB

        // --- stage K (identity copy, pre-swizzled) + V^T (row gather)
        GLDS16(kg + kt0 * 64,       ksl);
        GLDS16(kg + kt0 * 64 + 512, ksl + 512);
        {
            _Float16* vtl = vbuf + vrow * 64 + (l & 7) * 8;
            GLDS16(vg + kt0,             vtl);
            GLDS16(vg + kt0 + 8 * 2048,  vtl + 512);
        }
        __syncthreads();   // B1: tiles visible

        // --- S^T = K · Q^T  (rows=key, cols=query)
        f32x4 st[2][4];    // [m0][n0]
#pragma unroll
        for (int n0 = 0; n0 < 4; ++n0) {
            const int p0 = (q4 ^ a7) << 3;
            f16x8 kf0 = *(const f16x8*)&Ks[(n0 * 16 + a) * 64 + p0];
            f16x8 kf1 = *(const f16x8*)&Ks[(n0 * 16 + a) * 64 + (p0 ^ 32)];
#pragma unroll
            for (int m0 = 0; m0 < 2; ++m0) {
                f32x4 c = (m0 == 0) ? (f32x4){0.f, 0.f, 0.f, 0.f}
                                    : (f32x4){0.f, 0.f, 0.f, 0.f};
                c = MFMA16(kf0, qf[m0][0], c);
                c = MFMA16(kf1, qf[m0][1], c);
                st[m0][n0] = c;
            }
        }
        __syncthreads();   // B2: Ks reads drained (next iter restages Ks)

        // --- scale + causal mask + per-lane online softmax
#pragma unroll
        for (int m0 = 0; m0 < 2; ++m0) {
            const int qmin = qw0 + m0 * 16;
            if (kt0 + 63 > qmin) {
#pragma unroll
                for (int n0 = 0; n0 < 4; ++n0)
#pragma unroll
                    for (int r = 0; r < 4; ++r) {
                        const int kgl = kt0 + n0 * 16 + q4 * 4 + r;
                        const int qgl = qmin + a;
                        st[m0][n0][r] = (kgl > qgl) ? MASK2 : st[m0][n0][r] * SCALE2;
                    }
            } else {
#pragma unroll
                for (int n0 = 0; n0 < 4; ++n0) st[m0][n0] *= SCALE2;
            }
            float mloc = fmaxf(fmaxf(fmaxf(st[m0][0][0], st[m0][0][1]), fmaxf(st[m0][0][2], st[m0][0][3])),
                               fmaxf(fmaxf(st[m0][1][0], st[m0][1][1]), fmaxf(st[m0][1][2], st[m0][1][3])));
            mloc = fmaxf(mloc,
                   fmaxf(fmaxf(fmaxf(st[m0][2][0], st[m0][2][1]), fmaxf(st[m0][2][2], st[m0][2][3])),
                         fmaxf(fmaxf(st[m0][3][0], st[m0][3][1]), fmaxf(st[m0][3][2], st[m0][3][3]))));
            mloc = fmaxf(mloc, __shfl_xor(mloc, 16));
            mloc = fmaxf(mloc, __shfl_xor(mloc, 32));
            const float nm = fmaxf(mrun[m0], mloc);
            const float al = EXP2F(mrun[m0] - nm);
            mrun[m0] = nm;
            float ls = 0.f;
#pragma unroll
            for (int n0 = 0; n0 < 4; ++n0)
#pragma unroll
                for (int r = 0; r < 4; ++r) {
                    const float p = EXP2F(st[m0][n0][r] - nm);
                    st[m0][n0][r] = p;
                    ls += p;
                }
            lrun[m0] = lrun[m0] * al + ls;   // per-lane partial (16 keys/lane)
#pragma unroll
            for (int c = 0; c < 4; ++c) O[m0][c] *= al;
        }

        // --- PV per m0 (sequential through the wave's 2KB P slice)
#pragma unroll
        for (int m0 = 0; m0 < 2; ++m0) {
            // write P[q=a][key] swizzled (within-wave WAR/RAW ordered by DS pipe)
#pragma unroll
            for (int n0 = 0; n0 < 4; ++n0)
#pragma unroll
                for (int r = 0; r < 4; ++r) {
                    const int key = n0 * 16 + q4 * 4 + r;
                    const int pos = (key >> 3) ^ a7;
                    pbuf[a * 64 + pos * 8 + (key & 7)] = (_Float16)st[m0][n0][r];
                }
            const int pp = (q4 ^ a7) << 3;
            f16x8 pf0 = *(const f16x8*)&pbuf[a * 64 + pp];
            f16x8 pf1 = *(const f16x8*)&pbuf[a * 64 + (pp ^ 32)];
#pragma unroll
            for (int c = 0; c < 4; ++c) {
                f16x8 vf0 = *(const f16x8*)&vbuf[(c * 16 + a) * 64 + pp];
                f16x8 vf1 = *(const f16x8*)&vbuf[(c * 16 + a) * 64 + (pp ^ 32)];
                O[m0][c] = MFMA16(vf0, pf0, O[m0][c]);
                O[m0][c] = MFMA16(vf1, pf1, O[m0][c]);
            }
        }
    }

    // --- epilogue: finish l, store O^T scalar with gemm-A swizzle on ctx
#pragma unroll
    for (int m0 = 0; m0 < 2; ++m0) {
        float lt = lrun[m0];
        lt += __shfl_xor(lt, 16);
        lt += __shfl_xor(lt, 32);
        const float inv = 1.0f / lt;
        const size_t row = (size_t)b * SEQ + qw0 + m0 * 16 + a;
#pragma unroll
        for (int c = 0; c < 4; ++c)
#pragma unroll
            for (int r = 0; r < 4; ++r) {
                const int d = c * 16 + q4 * 4 + r;
                const int kcol = h * 64 + (d & ~31)
                               + ((((d >> 3) & 3) ^ (a & 3)) << 3) + (d & 7);
                ctx[row * HID + kcol] = (_Float16)(O[m0][c][r] * inv);
            }
    }
}

// ---------------------------------------------------------------------------
extern "C" void kernel_launch(void* const* d_in, const int* in_sizes, int n_in,
                              void* d_out, int out_size, void* d_ws, size_t ws_size,
                              hipStream_t stream) {
    const float* hs   = (const float*)d_in[0];
    const float* Wqkv = (const float*)d_in[2];
    const float* bqkv = (const float*)d_in[3];
    const float* Wd   = (const float*)d_in[4];
    const float* bd   = (const float*)d_in[5];

    _Float16* A_h   = (_Float16*)d_ws;                       // 4096x1024 (swizzled)
    _Float16* WqkvT = A_h + (size_t)MTOT * HID;              // 3072x1024 (swizzled)
    _Float16* WdT   = WqkvT + (size_t)QKVN * HID;            // 1024x1024 (swizzled)
    _Float16* qbuf  = WdT + (size_t)HID * HID;               // q | k(sw) | vT(sw)
    _Float16* ctxb  = qbuf + 3 * HBUF;                       // 4096x1024 (swizzled)

    convert_f32_f16<<<(MTOT * HID / 8) / 256, 256, 0, stream>>>(hs, A_h);
    transpose_convert<<<dim3(QKVN / 32, HID / 32), 256, 0, stream>>>(Wqkv, WqkvT, HID, QKVN);
    transpose_convert<<<dim3(HID / 32, HID / 32), 256, 0, stream>>>(Wd, WdT, HID, HID);

    mfma_gemm<0><<<dim3(QKVN / 128, MTOT / 128), 256, 0, stream>>>(
        A_h, WqkvT, bqkv, (void*)qbuf, MTOT, QKVN, HID);

    attn_mfma<<<dim3(SEQ / 128, NHEAD, BATCH), 256, 0, stream>>>(
        qbuf, qbuf + HBUF, qbuf + 2 * HBUF, ctxb);

    mfma_gemm<1><<<dim3(HID / 128, MTOT / 128), 256, 0, stream>>>(
        ctxb, WdT, bd, d_out, MTOT, HID, HID);
}

// Round 4
// 216.778 us; speedup vs baseline: 5.7204x; 1.1212x over previous
//
#include <hip/hip_runtime.h>
#include <math.h>

#define BATCH 2
#define SEQ   2048
#define HID   1024
#define NHEAD 16
#define HDIM  64
#define MTOT  (BATCH * SEQ)   // 4096
#define QKVN  (3 * HID)       // 3072
#define HBUF  ((size_t)BATCH * NHEAD * SEQ * HDIM)   // elems per q/k/v/vT buf

typedef _Float16 f16x8 __attribute__((ext_vector_type(8)));
typedef _Float16 f16x4 __attribute__((ext_vector_type(4)));
typedef float    f32x4 __attribute__((ext_vector_type(4)));

#define MFMA16(a, b, c) __builtin_amdgcn_mfma_f32_16x16x32_f16((a), (b), (c), 0, 0, 0)

#define GLDS16(gp, lp) __builtin_amdgcn_global_load_lds( \
    (const __attribute__((address_space(1))) void*)(gp), \
    (__attribute__((address_space(3))) void*)(lp), 16, 0, 0)

#if __has_builtin(__builtin_amdgcn_exp2f)
#define EXP2F(x) __builtin_amdgcn_exp2f(x)
#else
#define EXP2F(x) exp2f(x)
#endif

#define SCALE2 0.18033688011f     // 0.125 * log2(e)
#define MASK2  -14426.950408f     // -10000 * log2(e)

// ---------------------------------------------------------------------------
// fp32 -> fp16 convert with GEMM-A swizzle: within each 32-elem k-group,
// 16B chunk c of row m is stored at position c ^ (m&3).  (K = 1024.)
// ---------------------------------------------------------------------------
__global__ __launch_bounds__(256) void convert_f32_f16(
    const float* __restrict__ in, _Float16* __restrict__ out)
{
    const int ci = blockIdx.x * 256 + threadIdx.x;      // global chunk id
    const int m = ci >> 7, cc = ci & 127;               // 128 chunks per row
    const int g = cc >> 2, c = cc & 3;
    const float* src = in + (size_t)m * 1024 + cc * 8;
    f16x8 o;
#pragma unroll
    for (int j = 0; j < 8; ++j) o[j] = (_Float16)src[j];
    *(f16x8*)(out + (size_t)m * 1024 + g * 32 + ((c ^ (m & 3)) << 3)) = o;
}

// ---------------------------------------------------------------------------
// fp32 [K][N] -> fp16 [N][K] transpose-convert + B-operand chunk swizzle.
// ---------------------------------------------------------------------------
__global__ __launch_bounds__(256) void transpose_convert(
    const float* __restrict__ in, _Float16* __restrict__ out, int K, int N)
{
    __shared__ _Float16 T[32][36];
    const int k0 = blockIdx.y * 32, n0 = blockIdx.x * 32;
    const int tid = threadIdx.x;
    {
        const int r = tid >> 3, c4 = (tid & 7) * 4;
        float4 v = *(const float4*)(in + (size_t)(k0 + r) * N + n0 + c4);
        T[r][c4 + 0] = (_Float16)v.x;
        T[r][c4 + 1] = (_Float16)v.y;
        T[r][c4 + 2] = (_Float16)v.z;
        T[r][c4 + 3] = (_Float16)v.w;
    }
    __syncthreads();
    {
        const int nn = tid >> 3, k4 = (tid & 7) * 4;
        const int n = n0 + nn;
        f16x4 o;
        o[0] = T[k4 + 0][nn]; o[1] = T[k4 + 1][nn];
        o[2] = T[k4 + 2][nn]; o[3] = T[k4 + 3][nn];
        const int pos = ((k4 >> 3) ^ (n & 3)), half = (k4 >> 2) & 1;
        *(f16x4*)(out + (size_t)n * K + k0 + pos * 8 + half * 4) = o;
    }
}

// ---------------------------------------------------------------------------
// v [b,h,s,d] -> vT [b,h,d,s] with per-row chunk swizzle (pos = schunk^(d&7)).
// 64x64 tiles through LDS; coalesced global read and write.
// ---------------------------------------------------------------------------
__global__ __launch_bounds__(256) void transpose_v(
    const _Float16* __restrict__ v, _Float16* __restrict__ vt)
{
    __shared__ _Float16 T[64 * 64];
    const int s0 = blockIdx.x * 64;
    const size_t bh = (size_t)blockIdx.z * NHEAD + blockIdx.y;
    const int tid = threadIdx.x;
#pragma unroll
    for (int pass = 0; pass < 2; ++pass) {
        const int s = pass * 32 + (tid >> 3);
        const int c = tid & 7;
        f16x8 val = *(const f16x8*)(v + (bh * SEQ + s0 + s) * 64 + c * 8);
#pragma unroll
        for (int j = 0; j < 8; ++j) {
            const int d = c * 8 + j;
            T[d * 64 + (((s >> 3) ^ (d & 7)) << 3) + (s & 7)] = val[j];
        }
    }
    __syncthreads();
#pragma unroll
    for (int pass = 0; pass < 2; ++pass) {
        const int d = pass * 32 + (tid >> 3);
        const int cp = tid & 7;
        f16x8 val = *(const f16x8*)&T[d * 64 + cp * 8];
        *(f16x8*)(vt + (bh * 64 + d) * SEQ + s0 + cp * 8) = val;
    }
}

// ---------------------------------------------------------------------------
// MFMA fp16 GEMM, TMx128xBK32, swizzled LDS (conflict-free b128 reads).
// A and Bt pre-swizzled in global -> global_load_lds is an identity copy.
// EPI=0 (TM=128): scatter to q (plain) / k (row-swizzled) / v (plain).
// EPI=1: plain fp32 [M][N] store.
// ---------------------------------------------------------------------------
template<int EPI, int TM>
__global__ __launch_bounds__(256) void mfma_gemm(
    const _Float16* __restrict__ A, const _Float16* __restrict__ Bt,
    const float* __restrict__ bias, void* __restrict__ Cout,
    int M, int N, int K)
{
    __shared__ _Float16 As[TM * 32];
    __shared__ _Float16 Bs[128 * 32];
    constexpr int TI = TM / 32;          // A-fragments per wave
    constexpr int AR = TM / 4;           // A rows staged per wave

    const int tid = threadIdx.x;
    const int w = tid >> 6, l = tid & 63;
    const int a = l & 15, q4 = l >> 4;
    const int m0 = blockIdx.y * TM, n0 = blockIdx.x * 128;
    const int wm = (w >> 1) * (TM / 2), wn = (w & 1) * 64;

    f32x4 acc[TI][4];
#pragma unroll
    for (int i = 0; i < TI; ++i)
#pragma unroll
        for (int j = 0; j < 4; ++j) acc[i][j] = (f32x4){0.f, 0.f, 0.f, 0.f};

    const _Float16* gA = A + (size_t)(m0 + w * AR + (l >> 2)) * K + (l & 3) * 8;
    const _Float16* gB = Bt + (size_t)(n0 + w * 32 + (l >> 2)) * K + (l & 3) * 8;
    _Float16* sA = As + w * AR * 32;
    _Float16* sB = Bs + w * 1024;

    for (int k0 = 0; k0 < K; k0 += 32) {
#pragma unroll
        for (int u = 0; u < TM / 64; ++u)
            GLDS16(gA + (size_t)u * 16 * K + k0, sA + u * 512);
        GLDS16(gB + k0,          sB);
        GLDS16(gB + 16 * K + k0, sB + 512);
        __syncthreads();

        f16x8 af[TI], bf[4];
        const int pa = (q4 ^ (a & 3)) << 3;
#pragma unroll
        for (int i = 0; i < TI; ++i)
            af[i] = *(const f16x8*)&As[(wm + 16 * i + a) * 32 + pa];
#pragma unroll
        for (int j = 0; j < 4; ++j)
            bf[j] = *(const f16x8*)&Bs[(wn + 16 * j + a) * 32 + pa];
#pragma unroll
        for (int i = 0; i < TI; ++i)
#pragma unroll
            for (int j = 0; j < 4; ++j)
                acc[i][j] = MFMA16(af[i], bf[j], acc[i][j]);
        __syncthreads();
    }

    if (EPI == 0) {
        _Float16* base = (_Float16*)Cout;
#pragma unroll
        for (int j = 0; j < 4; ++j) {
            const int n = n0 + wn + 16 * j + a;
            const float bv = bias[n];
            const int t = n >> 10, h = (n >> 6) & 15, d = n & 63;
#pragma unroll
            for (int i = 0; i < TI; ++i) {
#pragma unroll
                for (int r = 0; r < 4; ++r) {
                    const int m = m0 + wm + 16 * i + q4 * 4 + r;
                    const int bb = m >> 11, s = m & 2047;
                    const _Float16 val = (_Float16)(acc[i][j][r] + bv);
                    if (t == 1) {   // k: row-swizzled chunks
                        const int dk = ((((d >> 3) ^ (s & 7)) & 7) << 3) | (d & 7);
                        base[HBUF + ((size_t)(bb * 16 + h) * 2048 + s) * 64 + dk] = val;
                    } else {        // q (t=0) and v (t=2): plain [b,h,s,d]
                        base[(size_t)t * HBUF +
                             ((size_t)(bb * 16 + h) * 2048 + s) * 64 + d] = val;
                    }
                }
            }
        }
    } else {
        float* C = (float*)Cout;
#pragma unroll
        for (int j = 0; j < 4; ++j) {
            const int n = n0 + wn + 16 * j + a;
            const float bv = bias[n];
#pragma unroll
            for (int i = 0; i < TI; ++i)
#pragma unroll
                for (int r = 0; r < 4; ++r) {
                    const int m = m0 + wm + 16 * i + q4 * 4 + r;
                    C[(size_t)m * N + n] = acc[i][j][r] + bv;
                }
        }
    }
}

// ---------------------------------------------------------------------------
// Paired-tile transposed-MFMA flash attention (uniform work per block).
// Block p handles query tiles lo=p and hi=31-p (64 queries each); lo's causal
// key range [0, 64(p+1)) is a subset of hi's [0, 64(32-p)), so both halves
// consume the same staged K/V tiles: per tile t, hi always computes; lo when
// t<=p. Total work = 33 half-tiles per block, exactly uniform -> 512 blocks =
// 2 resident rounds per CU, no tail.
// S^T = MFMA(Kf,Qf) (cols=query=lane -> per-lane softmax stats);
// O^T = MFMA(VTf,Pf); V^T pre-transposed+swizzled in global.
// LDS 24KB: Ks 8K + VT dbuf 16K; P uses wave slice of the inactive VT buffer.
// ---------------------------------------------------------------------------
__global__ __launch_bounds__(256) void attn_mfma(
    const _Float16* __restrict__ qb, const _Float16* __restrict__ kb,
    const _Float16* __restrict__ vtb, _Float16* __restrict__ ctx)
{
    __shared__ _Float16 Ks[64 * 64];
    __shared__ _Float16 VT[2][64 * 64];

    const int p = blockIdx.x;                  // pair index 0..15
    const int h = blockIdx.y, b = blockIdx.z;
    const int tid = threadIdx.x;
    const int w = tid >> 6, l = tid & 63;
    const int a = l & 15, q4 = l >> 4, a7 = a & 7;
    const size_t bh  = ((size_t)b * NHEAD + h) * SEQ;
    const size_t bhd = ((size_t)b * NHEAD + h) * 64;

    const int qHi = (31 - p) * 64 + w * 16;    // wave's hi-query base
    const int qLo = p * 64 + w * 16;
    const int ntiles = 32 - p;

    f16x8 qfh[2], qfl[2];
    {
        const _Float16* qp = qb + (bh + qHi + a) * 64;
        qfh[0] = *(const f16x8*)(qp + q4 * 8);
        qfh[1] = *(const f16x8*)(qp + 32 + q4 * 8);
        const _Float16* ql = qb + (bh + qLo + a) * 64;
        qfl[0] = *(const f16x8*)(ql + q4 * 8);
        qfl[1] = *(const f16x8*)(ql + 32 + q4 * 8);
    }

    f32x4 Oh[4], Ol[4];
#pragma unroll
    for (int c = 0; c < 4; ++c) {
        Oh[c] = (f32x4){0.f, 0.f, 0.f, 0.f};
        Ol[c] = (f32x4){0.f, 0.f, 0.f, 0.f};
    }
    float mh = -INFINITY, lh = 0.f, ml = -INFINITY, ll = 0.f;

    const _Float16* kg = kb + (bh + w * 16) * 64 + l * 8;
    _Float16* ksl = Ks + w * 16 * 64 + l * 8;
    const int vrow = w * 16 + (l >> 3);
    const _Float16* vg = vtb + (bhd + vrow) * 2048 + (l & 7) * 8;

    const int p0 = (q4 ^ a7) << 3;

    for (int t = 0; t < ntiles; ++t) {
        const int kt0 = t * 64;
        _Float16* vbuf = &VT[t & 1][0];
        _Float16* pbuf = &VT[(t + 1) & 1][0] + w * 16 * 64;   // wave-private

        GLDS16(kg + (size_t)kt0 * 64,       ksl);
        GLDS16(kg + (size_t)kt0 * 64 + 512, ksl + 512);
        {
            _Float16* vtl = vbuf + vrow * 64 + (l & 7) * 8;
            GLDS16(vg + kt0,            vtl);
            GLDS16(vg + kt0 + 8 * 2048, vtl + 512);
        }
        __syncthreads();   // B1: tiles visible

        const bool doLo = (t <= p);
        f32x4 sh[4], sl[4];
#pragma unroll
        for (int n0 = 0; n0 < 4; ++n0) {
            f16x8 kf0 = *(const f16x8*)&Ks[(n0 * 16 + a) * 64 + p0];
            f16x8 kf1 = *(const f16x8*)&Ks[(n0 * 16 + a) * 64 + (p0 ^ 32)];
            f32x4 c = (f32x4){0.f, 0.f, 0.f, 0.f};
            c = MFMA16(kf0, qfh[0], c);
            c = MFMA16(kf1, qfh[1], c);
            sh[n0] = c;
            if (doLo) {
                f32x4 d = (f32x4){0.f, 0.f, 0.f, 0.f};
                d = MFMA16(kf0, qfl[0], d);
                d = MFMA16(kf1, qfl[1], d);
                sl[n0] = d;
            }
        }
        __syncthreads();   // B2: Ks reads drained before next restage

        // ---- softmax + P + PV for one half
        auto half_step = [&](f32x4 st[4], float& mrun, float& lrun, f32x4 O[4],
                             const bool maskTile, const int qbase) {
            if (maskTile) {
#pragma unroll
                for (int n0 = 0; n0 < 4; ++n0)
#pragma unroll
                    for (int r = 0; r < 4; ++r) {
                        const int kgl = kt0 + n0 * 16 + q4 * 4 + r;
                        st[n0][r] = (kgl > qbase + a) ? MASK2 : st[n0][r] * SCALE2;
                    }
            } else {
#pragma unroll
                for (int n0 = 0; n0 < 4; ++n0) st[n0] *= SCALE2;
            }
            float mx = fmaxf(fmaxf(fmaxf(st[0][0], st[0][1]), fmaxf(st[0][2], st[0][3])),
                             fmaxf(fmaxf(st[1][0], st[1][1]), fmaxf(st[1][2], st[1][3])));
            mx = fmaxf(mx,
                 fmaxf(fmaxf(fmaxf(st[2][0], st[2][1]), fmaxf(st[2][2], st[2][3])),
                       fmaxf(fmaxf(st[3][0], st[3][1]), fmaxf(st[3][2], st[3][3]))));
            mx = fmaxf(mx, __shfl_xor(mx, 16));
            mx = fmaxf(mx, __shfl_xor(mx, 32));
            const float nm = fmaxf(mrun, mx);
            const float al = EXP2F(mrun - nm);
            mrun = nm;
            float ls = 0.f;
#pragma unroll
            for (int n0 = 0; n0 < 4; ++n0)
#pragma unroll
                for (int r = 0; r < 4; ++r) {
                    const float pe = EXP2F(st[n0][r] - nm);
                    st[n0][r] = pe;
                    ls += pe;
                }
            lrun = lrun * al + ls;
#pragma unroll
            for (int c = 0; c < 4; ++c) O[c] *= al;
            // P write: keys 16n0+4q4..+3 are consecutive -> one b64 per n0
#pragma unroll
            for (int n0 = 0; n0 < 4; ++n0) {
                f16x4 pk;
#pragma unroll
                for (int r = 0; r < 4; ++r) pk[r] = (_Float16)st[n0][r];
                const int pos = (2 * n0 + (q4 >> 1)) ^ a7;
                *(f16x4*)&pbuf[a * 64 + pos * 8 + ((q4 & 1) << 2)] = pk;
            }
            f16x8 pf0 = *(const f16x8*)&pbuf[a * 64 + p0];
            f16x8 pf1 = *(const f16x8*)&pbuf[a * 64 + (p0 ^ 32)];
#pragma unroll
            for (int c = 0; c < 4; ++c) {
                f16x8 vf0 = *(const f16x8*)&vbuf[(c * 16 + a) * 64 + p0];
                f16x8 vf1 = *(const f16x8*)&vbuf[(c * 16 + a) * 64 + (p0 ^ 32)];
                O[c] = MFMA16(vf0, pf0, O[c]);
                O[c] = MFMA16(vf1, pf1, O[c]);
            }
        };

        half_step(sh, mh, lh, Oh, t == ntiles - 1, qHi);
        if (doLo) half_step(sl, ml, ll, Ol, t == p, qLo);
    }

    // ---- epilogue: finish l, store O^T with gemm-A swizzle on ctx
    auto finish = [&](float lrun, const f32x4 O[4], const int qbase) {
        float lt = lrun;
        lt += __shfl_xor(lt, 16);
        lt += __shfl_xor(lt, 32);
        const float inv = 1.0f / lt;
        const size_t row = (size_t)b * SEQ + qbase + a;
#pragma unroll
        for (int c = 0; c < 4; ++c)
#pragma unroll
            for (int r = 0; r < 4; ++r) {
                const int d = c * 16 + q4 * 4 + r;
                const int kcol = h * 64 + (d & ~31)
                               + ((((d >> 3) & 3) ^ (a & 3)) << 3) + (d & 7);
                ctx[row * HID + kcol] = (_Float16)(O[c][r] * inv);
            }
    };
    finish(lh, Oh, qHi);
    finish(ll, Ol, qLo);
}

// ---------------------------------------------------------------------------
extern "C" void kernel_launch(void* const* d_in, const int* in_sizes, int n_in,
                              void* d_out, int out_size, void* d_ws, size_t ws_size,
                              hipStream_t stream) {
    const float* hs   = (const float*)d_in[0];
    const float* Wqkv = (const float*)d_in[2];
    const float* bqkv = (const float*)d_in[3];
    const float* Wd   = (const float*)d_in[4];
    const float* bd   = (const float*)d_in[5];

    _Float16* A_h   = (_Float16*)d_ws;                       // 4096x1024 (swizzled)
    _Float16* WqkvT = A_h + (size_t)MTOT * HID;              // 3072x1024 (swizzled)
    _Float16* WdT   = WqkvT + (size_t)QKVN * HID;            // 1024x1024 (swizzled)
    _Float16* qbuf  = WdT + (size_t)HID * HID;               // q | k(sw) | v | vT(sw)
    _Float16* ctxb  = qbuf + 4 * HBUF;                       // 4096x1024 (swizzled)

    convert_f32_f16<<<(MTOT * HID / 8) / 256, 256, 0, stream>>>(hs, A_h);
    transpose_convert<<<dim3(QKVN / 32, HID / 32), 256, 0, stream>>>(Wqkv, WqkvT, HID, QKVN);
    transpose_convert<<<dim3(HID / 32, HID / 32), 256, 0, stream>>>(Wd, WdT, HID, HID);

    mfma_gemm<0, 128><<<dim3(QKVN / 128, MTOT / 128), 256, 0, stream>>>(
        A_h, WqkvT, bqkv, (void*)qbuf, MTOT, QKVN, HID);

    transpose_v<<<dim3(SEQ / 64, NHEAD, BATCH), 256, 0, stream>>>(
        qbuf + 2 * HBUF, qbuf + 3 * HBUF);

    attn_mfma<<<dim3(16, NHEAD, BATCH), 256, 0, stream>>>(
        qbuf, qbuf + HBUF, qbuf + 3 * HBUF, ctxb);

    mfma_gemm<1, 64><<<dim3(HID / 128, MTOT / 64), 256, 0, stream>>>(
        ctxb, WdT, bd, d_out, MTOT, HID, HID);
}